// Round 4
// baseline (4193.147 us; speedup 1.0000x reference)
//
#include <hip/hip_runtime.h>
#include <hip/hip_bf16.h>

// LSTM chain: B=256, S=512, H=256, V=128.
// Round 3 (re-run; round 3 bench was GPUAcquisitionTimeout — never executed):
// actually get W VGPR-resident (round 2 failed: compiler sank the wf
// loads back into the loop -> VGPR_Count=64, W re-streamed from L2 every step).
//   - asm volatile("" : "+v"(frag)) after the W loads makes them opaque: no
//     remat/sink. 32 frags = 128 VGPRs held for all 512 steps.
//   - zx repacked as zx2[v][col][4] -> one dwordx4 per (row j) instead of 16
//     scalar loads; prefetched one step ahead (independent of recurrence).
//   - nontemporal output stores.
// Structure: 16 blocks x 1024 threads (16 waves). Block owns 16 batch rows.
// Wave w owns z-tiles (gate q, colblock w), q=0..3. Per step: 8x ds_read_b128
// A-frags (h) from LDS ping-pong, 32 MFMA 16x16x32 bf16, fp32 gates, c in regs,
// h written back to LDS directly in A-fragment layout. One barrier/step.
// A/B fragment k-order uses one consistent bijection k = 32*s + 8*(lane>>4)+elem
// on both operands (correct for any true HW intra-fragment k-perm).
// C/D layout (HW-verified): col = lane&15, row = 4*(lane>>4) + reg.

#define HID    256
#define FOURH  1024
#define SLEN   512
#define NVOCAB 128
#define BSZ    16     // batch rows per block

typedef __attribute__((ext_vector_type(8))) __bf16 bf16x8;
typedef __attribute__((ext_vector_type(4))) float  f32x4;

__device__ __forceinline__ unsigned short f2bf(float x) {
  unsigned int u = __builtin_bit_cast(unsigned int, x);
  u = (u + 0x7FFFu + ((u >> 16) & 1u)) >> 16;   // RNE
  return (unsigned short)u;
}
__device__ __forceinline__ float sigmoid_(float x) {
  return __builtin_amdgcn_rcpf(1.f + __expf(-x));
}
__device__ __forceinline__ float tanh_(float x) {
  return 1.f - 2.f * __builtin_amdgcn_rcpf(__expf(2.f * x) + 1.f);
}

// ---------------- prep: zx2 table + Wh bf16 fragment repack ----------------
__global__ __launch_bounds__(256) void lstm_prep(
    const float* __restrict__ emb, const float* __restrict__ W,
    const float* __restrict__ b, float* __restrict__ zx2,
    unsigned short* __restrict__ Wb)
{
  const int blk = blockIdx.x;
  if (blk < NVOCAB) {
    // zx2[v][c][q] = sum_k emb[v][k] * W[(H+k)][q*256+c] + b[q*256+c]
    __shared__ float ev[HID];
    const int v = blk;
    for (int i = threadIdx.x; i < HID; i += 256) ev[i] = emb[v * HID + i];
    __syncthreads();
    for (int q = 0; q < 4; ++q) {
      const int col = q * 256 + threadIdx.x;
      float acc = b[col];
      #pragma unroll 4
      for (int k = 0; k < HID; ++k)
        acc += ev[k] * W[(HID + k) * FOURH + col];   // coalesced across threads
      zx2[((size_t)v * 256 + threadIdx.x) * 4 + q] = acc;
    }
  } else {
    // Wb fragment layout: frag(tile c, kstep s): element (g, r, j) at
    //   (((c*8+s)*4+g)*16+r)*8 + j  holds  Wh[k = 32s+8g+j][zcol = 16c+r]
    int idx = (blk - NVOCAB) * 256 + threadIdx.x;    // 0..32767 = (c,s,g,r)
    const int c = idx >> 9;
    const int rem = idx & 511;
    const int s = rem >> 6, gg = (rem >> 4) & 3, r = rem & 15;
    const int col = 16 * c + r;
    #pragma unroll
    for (int j = 0; j < 8; ++j) {
      const int k = 32 * s + 8 * gg + j;
      Wb[(((c * 8 + s) * 4 + gg) * 16 + r) * 8 + j] = f2bf(W[k * FOURH + col]);
    }
  }
}

// ---------------- sequential recurrence ----------------
__global__ __launch_bounds__(1024, 1) void lstm_seq(
    const int* __restrict__ tokens, const float* __restrict__ zx2,
    const unsigned short* __restrict__ Wb, float* __restrict__ out)
{
  // h fragments, ping-pong: element ((s*4+g)*16+r)*8+j = h[row=r][k=32s+8g+j]
  __shared__ __align__(16) unsigned short hbuf[2][4096];
  const int tid = threadIdx.x;
  const int w = tid >> 6, l = tid & 63;
  const int g = l >> 4, r = l & 15;
  const int b0 = blockIdx.x * BSZ;
  const int row4 = 4 * g;                 // D-frag local row base (rows 4g+j)

  for (int i = tid; i < 2 * 4096; i += 1024) ((unsigned short*)hbuf)[i] = 0;

  // --- W fragments resident in VGPRs for the entire sequence ---
  // wave w owns z-tiles (q, cb=w) -> tile index c = 16q + w; 32 frags = 128 VGPRs.
  f32x4 wf[32];
  const unsigned short* wl = Wb + (size_t)l * 8;
  #pragma unroll
  for (int q = 0; q < 4; ++q)
    #pragma unroll
    for (int s = 0; s < 8; ++s)
      wf[q * 8 + s] = *reinterpret_cast<const f32x4*>(
          wl + (size_t)(16 * q + w) * 4096 + s * 512);
  // Opaque barrier: forbids remat/sinking of the W loads into the time loop.
  #pragma unroll
  for (int i = 0; i < 32; ++i) asm volatile("" : "+v"(wf[i]));

  float cst[4] = {0.f, 0.f, 0.f, 0.f};    // c state (rows 4g+j, col colw)

  const int colw = 16 * w + r;            // this thread's h column 0..255
  const int s4 = colw >> 5, gg = (colw >> 3) & 3, jj = colw & 7;

  // per-row token / output pointers
  const int* trp[4];
  float* op[4];
  #pragma unroll
  for (int j = 0; j < 4; ++j) {
    trp[j] = tokens + (size_t)(b0 + row4 + j) * SLEN;
    op[j]  = out + (size_t)(b0 + row4 + j) * (SLEN * HID) + colw;
  }

  // prologue: prefetch t=0 token-projection rows
  f32x4 zxc[4];
  #pragma unroll
  for (int j = 0; j < 4; ++j) {
    const int tk = trp[j][0];
    zxc[j] = *reinterpret_cast<const f32x4*>(zx2 + ((size_t)tk * 256 + colw) * 4);
  }

  __syncthreads();

  for (int t = 0; t < SLEN; ++t) {
    const int pp = t & 1;

    // -- prefetch step t+1's zx rows (independent of the recurrence) --
    const int tn = (t + 1 < SLEN) ? t + 1 : SLEN - 1;
    f32x4 zxn[4];
    #pragma unroll
    for (int j = 0; j < 4; ++j) {
      const int tk = trp[j][tn];
      zxn[j] = *reinterpret_cast<const f32x4*>(zx2 + ((size_t)tk * 256 + colw) * 4);
    }

    // -- A fragments: 8 x ds_read_b128, fully linear (conflict-free) --
    bf16x8 a[8];
    #pragma unroll
    for (int s = 0; s < 8; ++s)
      a[s] = *reinterpret_cast<const bf16x8*>(&hbuf[pp][(s * 64 + l) * 8]);

    // -- 4 z-tiles (q, cb=w); B operands resident in VGPRs --
    f32x4 acc[4];
    #pragma unroll
    for (int q = 0; q < 4; ++q) {
      f32x4 A = {0.f, 0.f, 0.f, 0.f};
      #pragma unroll
      for (int s = 0; s < 8; ++s)
        A = __builtin_amdgcn_mfma_f32_16x16x32_bf16(
            a[s], __builtin_bit_cast(bf16x8, wf[q * 8 + s]), A, 0, 0, 0);
      acc[q] = A;
    }

    // -- gates (fp32), c in regs, write h to out + next-step A-fragments --
    #pragma unroll
    for (int j = 0; j < 4; ++j) {
      const float zi = acc[0][j] + zxc[j][0];
      const float zf = acc[1][j] + zxc[j][1];
      const float zo = acc[2][j] + zxc[j][2];
      const float zu = acc[3][j] + zxc[j][3];
      const float iv = sigmoid_(zi);
      const float fv = sigmoid_(zf);
      const float ov = sigmoid_(zo);
      const float uv = tanh_(zu);
      const float cn = iv * uv + fv * cst[j];
      cst[j] = cn;
      const float hn = ov * tanh_(cn);
      __builtin_nontemporal_store(hn, op[j]);
      op[j] += HID;
      hbuf[pp ^ 1][((s4 * 4 + gg) * 16 + (row4 + j)) * 8 + jj] = f2bf(hn);
    }

    // rotate prefetched zx
    #pragma unroll
    for (int j = 0; j < 4; ++j) zxc[j] = zxn[j];

    __syncthreads();   // single barrier/step (ping-pong makes it sufficient)
  }
}

extern "C" void kernel_launch(void* const* d_in, const int* in_sizes, int n_in,
                              void* d_out, int out_size, void* d_ws, size_t ws_size,
                              hipStream_t stream) {
  const int*   tokens = (const int*)d_in[0];
  const float* emb    = (const float*)d_in[1];
  const float* W      = (const float*)d_in[2];
  const float* b      = (const float*)d_in[3];
  float* out = (float*)d_out;

  float*          zx2 = (float*)d_ws;                                 // 512 KB
  unsigned short* Wb  = (unsigned short*)((char*)d_ws + 512 * 1024);  // 512 KB

  lstm_prep<<<256, 256, 0, stream>>>(emb, W, b, zx2, Wb);
  lstm_seq<<<16, 1024, 0, stream>>>(tokens, zx2, Wb, out);
}